// Round 13
// baseline (570.629 us; speedup 1.0000x reference)
//
#include <hip/hip_runtime.h>
#include <cmath>

// Multi-scale residual VQ, round 13.
// R12 analysis: argbig at NP=2 saturates whichever single pipe streams E
// (LDS 128 B/cyc needed ~= LDS peak -> 63%; scalar-only hit K$ ceiling at
// 58% in R9). R13: HYBRID stream - even codes from LDS (uniform float4
// broadcasts), odd codes from the scalar K$ path. Ascending-v order and FMA
// chain structure preserved exactly (numpy tie semantics, bit-identical d).
// fuse_k unchanged (conv is DS/VALU balanced at 1 block/CU).

#define BB 64
#define CC 32
#define HH 16
#define VV 4096
#define NTOT (BB*CC*HH*HH)   // 524288

__device__ __forceinline__ double cubicw(double x) {
    x = fabs(x);
    const double a = -0.75;
    if (x <= 1.0) return ((a + 2.0) * x - (a + 3.0)) * x * x + 1.0;
    if (x < 2.0)  return (((a * x - 5.0 * a) * x + 8.0 * a) * x - 4.0 * a);
    return 0.0;
}

// monotone float->uint map: d1<d2 (finite) => ordf(d1)<ordf(d2)
__device__ __forceinline__ unsigned int ordf(float d) {
    unsigned int b = __float_as_uint(d);
    return (b & 0x80000000u) ? ~b : (b | 0x80000000u);
}

// init: f_rest=f, f_hat=0, e2 rows, and z for scale 0 (pn=1: per-(b,c) mean).
__global__ void init_k(const float* __restrict__ f, const float* __restrict__ E,
                       float* __restrict__ f_rest, float* __restrict__ f_hat,
                       float* __restrict__ e2, float* __restrict__ z) {
    int i = blockIdx.x * 256 + threadIdx.x;
    if (i < NTOT) { f_rest[i] = f[i]; f_hat[i] = 0.f; }
    if (i < VV) {
        float s = 0.f;
        #pragma unroll
        for (int c = 0; c < CC; ++c) { float e = E[i * CC + c]; s += e * e; }
        e2[i] = s;
    }
    if (i < BB * CC) {
        const float* src = f + (size_t)i * (HH * HH);
        float s = 0.f;
        for (int j = 0; j < HH * HH; ++j) s += src[j];
        z[i] = s * (1.0f / 256.0f);
    }
}

// Small scales: grid (pn*pn, grp); block = 4 waves; each wave = same 64 points
// (one per lane), wave-specific code range (wave-uniform => scalar E loads).
__global__ __launch_bounds__(256, 4) void argsmall_k(const float* __restrict__ z,
        const float* __restrict__ E, const float* __restrict__ e2,
        unsigned long long* __restrict__ bestk, int M, int G, int gsz) {
    const int t = threadIdx.x;
    int m = blockIdx.x * 64 + (t & 63);
    int w = __builtin_amdgcn_readfirstlane(t >> 6);
    int wg = blockIdx.y * 4 + w;
    int v0 = wg * gsz;
    float zr[CC]; float z2 = 0.f;
    const float4* zp = (const float4*)(z + (size_t)m * CC);
    #pragma unroll
    for (int c4 = 0; c4 < 8; ++c4) {
        float4 v = zp[c4];
        zr[c4*4+0] = v.x; zr[c4*4+1] = v.y; zr[c4*4+2] = v.z; zr[c4*4+3] = v.w;
        z2 += v.x*v.x + v.y*v.y + v.z*v.z + v.w*v.w;
    }
    const float* e = E + (size_t)v0 * CC;
    float best = 3.4e38f; int bv = v0;
    for (int v = v0; v < v0 + gsz; v += 2, e += 2 * CC) {
        float a0 = 0.f, a1 = 0.f, b0 = 0.f, b1 = 0.f;
        #pragma unroll
        for (int c = 0; c < CC; c += 2) {
            a0 = fmaf(zr[c],   e[c],      a0);
            a1 = fmaf(zr[c+1], e[c+1],    a1);
            b0 = fmaf(zr[c],   e[CC+c],   b0);
            b1 = fmaf(zr[c+1], e[CC+c+1], b1);
        }
        float dA = fmaf(-2.f, a0 + a1, z2 + e2[v]);
        float dB = fmaf(-2.f, b0 + b1, z2 + e2[v+1]);
        if (dA < best) { best = dA; bv = v; }
        if (dB < best) { best = dB; bv = v + 1; }
    }
    bestk[(size_t)m * G + wg] = ((unsigned long long)ordf(best) << 32) |
                                (unsigned long long)(unsigned int)bv;
}

// Large scales: 2 points/thread; even codes streamed from LDS (uniform float4
// broadcasts), odd codes from scalar K$ path. Keys [m][G]. Ascending v order.
__global__ __launch_bounds__(256, 4) void argbig_k(const float* __restrict__ z,
        const float* __restrict__ E, const float* __restrict__ e2g,
        unsigned long long* __restrict__ bestk, int M, int G, int gsz) {
    __shared__ float s_e[64 * CC];    // even codes only (gsz/2 <= 64): 8 KB
    __shared__ float s_e2[128];
    const int T = gridDim.x * 256;
    const int g = blockIdx.y;
    const int v0 = g * gsz;
    {
        for (int i = threadIdx.x; i < (gsz >> 1) * 8; i += 256) {
            int j = i >> 3, part = i & 7;
            ((float4*)s_e)[i] = ((const float4*)(E + (size_t)(v0 + 2 * j) * CC))[part];
        }
        for (int i = threadIdx.x; i < gsz; i += 256) s_e2[i] = e2g[v0 + i];
    }
    int   mm[2];
    bool  act[2];
    float zr[2][CC];
    float z2[2];
    #pragma unroll
    for (int pt = 0; pt < 2; ++pt) {
        int m0 = blockIdx.x * 256 + threadIdx.x + pt * T;
        act[pt] = (m0 < M);
        int m = act[pt] ? m0 : M - 1;
        mm[pt] = m;
        const float4* zp = (const float4*)(z + (size_t)m * CC);
        float zz = 0.f;
        #pragma unroll
        for (int c4 = 0; c4 < 8; ++c4) {
            float4 v = zp[c4];
            zr[pt][c4*4+0] = v.x; zr[pt][c4*4+1] = v.y;
            zr[pt][c4*4+2] = v.z; zr[pt][c4*4+3] = v.w;
            zz += v.x*v.x + v.y*v.y + v.z*v.z + v.w*v.w;
        }
        z2[pt] = zz;
    }
    __syncthreads();
    float best[2]; int bv[2];
    #pragma unroll
    for (int pt = 0; pt < 2; ++pt) { best[pt] = 3.4e38f; bv[pt] = v0; }
    const float4* ev = (const float4*)s_e;
    for (int vi = 0; vi < gsz; vi += 2, ev += 8) {
        // even code (v0+vi) from LDS
        float a0 = 0.f, a1 = 0.f, b0 = 0.f, b1 = 0.f;
        #pragma unroll
        for (int q8 = 0; q8 < 8; ++q8) {
            float4 q = ev[q8];
            int c = q8 * 4;
            a0 = fmaf(zr[0][c],   q.x, a0);
            a1 = fmaf(zr[0][c+1], q.y, a1);
            a0 = fmaf(zr[0][c+2], q.z, a0);
            a1 = fmaf(zr[0][c+3], q.w, a1);
            b0 = fmaf(zr[1][c],   q.x, b0);
            b1 = fmaf(zr[1][c+1], q.y, b1);
            b0 = fmaf(zr[1][c+2], q.z, b0);
            b1 = fmaf(zr[1][c+3], q.w, b1);
        }
        // odd code (v0+vi+1) from global scalar path (wave-uniform address)
        const float* eo = E + (size_t)(v0 + vi + 1) * CC;
        float c0 = 0.f, c1 = 0.f, d0 = 0.f, d1 = 0.f;
        #pragma unroll
        for (int c = 0; c < CC; c += 2) {
            c0 = fmaf(zr[0][c],   eo[c],   c0);
            c1 = fmaf(zr[0][c+1], eo[c+1], c1);
            d0 = fmaf(zr[1][c],   eo[c],   d0);
            d1 = fmaf(zr[1][c+1], eo[c+1], d1);
        }
        float e2E = s_e2[vi], e2O = s_e2[vi + 1];
        float dEA = fmaf(-2.f, a0 + a1, z2[0] + e2E);
        float dEB = fmaf(-2.f, b0 + b1, z2[1] + e2E);
        float dOA = fmaf(-2.f, c0 + c1, z2[0] + e2O);
        float dOB = fmaf(-2.f, d0 + d1, z2[1] + e2O);
        int vE = v0 + vi, vO = v0 + vi + 1;
        if (dEA < best[0]) { best[0] = dEA; bv[0] = vE; }
        if (dOA < best[0]) { best[0] = dOA; bv[0] = vO; }
        if (dEB < best[1]) { best[1] = dEB; bv[1] = vE; }
        if (dOB < best[1]) { best[1] = dOB; bv[1] = vO; }
    }
    #pragma unroll
    for (int pt = 0; pt < 2; ++pt)
        if (act[pt])
            bestk[(size_t)mm[pt] * G + g] =
                ((unsigned long long)ordf(best[pt]) << 32) |
                (unsigned long long)(unsigned int)bv[pt];
}

// Fused: group-reduce keys ([m][G], vectorized when TPP==1) -> gather +
// separable bicubic (LDS, padded) -> 3x3 conv Phi (transposed conflict-free
// weights) -> f_hat/f_rest update -> emit next scale's z rows.
__global__ __launch_bounds__(256) void fuse_k(const unsigned long long* __restrict__ bestk,
                      const float* __restrict__ E,
                      const float* __restrict__ pw, const float* __restrict__ pb,
                      float* __restrict__ f_hat, float* __restrict__ f_rest,
                      float* __restrict__ z_next,
                      int pn, int G, int TPP, int kphi, int pnn) {
    __shared__ float s_buf[CC * 18 * 20];
    __shared__ float s_pw[CC * 9 * 8];      // transposed: [ci*9+tap][col]
    __shared__ int   s_idx[256];
    __shared__ float s_w[HH][4];
    __shared__ int   s_j[HH][4];
    __shared__ unsigned long long s_red[256];
    const int t   = threadIdx.x;
    const int cog = blockIdx.x;
    const int b   = blockIdx.y;
    const int P   = pn * pn;

    if (TPP == 1) {
        if (t < P) {
            int m = b * P + t;
            const ulonglong2* kp = (const ulonglong2*)(bestk + (size_t)m * G);
            unsigned long long bk = ~0ull;
            #pragma unroll 4
            for (int gg = 0; gg < (G >> 1); ++gg) {
                ulonglong2 o = kp[gg];
                unsigned long long mn = o.x < o.y ? o.x : o.y;
                if (mn < bk) bk = mn;
            }
            s_idx[t] = (int)(unsigned int)(bk & 0xffffffffull);
        }
    } else {
        int p = t / TPP, sub = t - p * TPP;
        unsigned long long bk = ~0ull;
        if (p < P) {
            const unsigned long long* kp = bestk + (size_t)(b * P + p) * G;
            for (int gg = sub; gg < G; gg += TPP) {
                unsigned long long o = kp[gg];
                if (o < bk) bk = o;
            }
        }
        s_red[t] = bk;
        __syncthreads();
        for (int s = TPP >> 1; s > 0; s >>= 1) {
            if (sub < s && p < P) {
                unsigned long long o = s_red[t + s];
                if (o < s_red[t]) s_red[t] = o;
            }
            __syncthreads();
        }
        if (t < P) s_idx[t] = (int)(unsigned int)(s_red[t * TPP] & 0xffffffffull);
    }
    if (t < HH) {
        double src = (t + 0.5) * (double)pn / 16.0 - 0.5;
        double fi = floor(src); int i0 = (int)fi; double tt = src - fi;
        #pragma unroll
        for (int k = 0; k < 4; ++k) {
            int j = i0 - 1 + k; j = j < 0 ? 0 : (j > pn - 1 ? pn - 1 : j);
            s_j[t][k] = j;
            s_w[t][k] = (float)cubicw((double)(k - 1) - tt);
        }
    }
    {
        const float* src = pw + ((size_t)(kphi * CC + cog * 8)) * CC * 9;
        for (int i = t; i < 8 * CC * 9; i += 256) {
            int col = i / (CC * 9);
            int r   = i - col * (CC * 9);
            s_pw[r * 8 + col] = src[i];
        }
    }
    __syncthreads();

    if (t < HH * pn) {
        int h = t / pn, q = t % pn;
        float acc[CC];
        #pragma unroll
        for (int c = 0; c < CC; ++c) acc[c] = 0.f;
        #pragma unroll
        for (int k = 0; k < 4; ++k) {
            float wv = s_w[h][k];
            int row = s_idx[s_j[h][k] * pn + q];
            const float4* er = (const float4*)(E + (size_t)row * CC);
            #pragma unroll
            for (int c4 = 0; c4 < CC / 4; ++c4) {
                float4 e4 = er[c4];
                acc[c4*4+0] = fmaf(wv, e4.x, acc[c4*4+0]);
                acc[c4*4+1] = fmaf(wv, e4.y, acc[c4*4+1]);
                acc[c4*4+2] = fmaf(wv, e4.z, acc[c4*4+2]);
                acc[c4*4+3] = fmaf(wv, e4.w, acc[c4*4+3]);
            }
        }
        #pragma unroll
        for (int c = 0; c < CC; ++c) s_buf[(c * HH + h) * pn + q] = acc[c];
    }
    __syncthreads();

    {
        int h = t >> 4, w = t & 15;
        float acc[CC];
        #pragma unroll
        for (int c = 0; c < CC; ++c) acc[c] = 0.f;
        #pragma unroll
        for (int k = 0; k < 4; ++k) {
            float wh = s_w[w][k];
            int j = s_j[w][k];
            #pragma unroll
            for (int c = 0; c < CC; ++c)
                acc[c] = fmaf(wh, s_buf[(c * HH + h) * pn + j], acc[c]);
        }
        __syncthreads();
        #pragma unroll
        for (int c = 0; c < CC; ++c) s_buf[(c * 18 + h + 1) * 20 + w + 1] = acc[c];
        if (w == 0) {
            #pragma unroll
            for (int c = 0; c < CC; ++c) s_buf[(c * 18 + h + 1) * 20] = 0.f;
        }
        if (w >= 13) {
            #pragma unroll
            for (int c = 0; c < CC; ++c) s_buf[(c * 18 + h + 1) * 20 + w + 4] = 0.f;
        }
        if (h == 0) {
            #pragma unroll
            for (int c = 0; c < CC; ++c) {
                s_buf[(c * 18) * 20 + w] = 0.f;
                if (w < 4) s_buf[(c * 18) * 20 + 16 + w] = 0.f;
            }
        }
        if (h == 15) {
            #pragma unroll
            for (int c = 0; c < CC; ++c) {
                s_buf[(c * 18 + 17) * 20 + w] = 0.f;
                if (w < 4) s_buf[(c * 18 + 17) * 20 + 16 + w] = 0.f;
            }
        }
    }
    __syncthreads();

    int col = t >> 5;
    int co  = cog * 8 + col;
    int s   = t & 31;
    int h   = s >> 1;
    int w0  = (s & 1) * 8;
    float acc[8];
    float bias = pb[kphi * CC + co];
    #pragma unroll
    for (int o = 0; o < 8; ++o) acc[o] = bias;
    for (int ci = 0; ci < CC; ++ci) {
        const float* wb = &s_pw[(ci * 9) * 8 + col];
        #pragma unroll
        for (int kh = 0; kh < 3; ++kh) {
            const float4* xr = (const float4*)&s_buf[(ci * 18 + h + kh) * 20 + w0];
            float4 a0 = xr[0], a1 = xr[1], a2 = xr[2];
            float xf[12] = {a0.x, a0.y, a0.z, a0.w, a1.x, a1.y, a1.z, a1.w,
                            a2.x, a2.y, a2.z, a2.w};
            float k0 = wb[(kh*3+0)*8], k1 = wb[(kh*3+1)*8], k2 = wb[(kh*3+2)*8];
            #pragma unroll
            for (int o = 0; o < 8; ++o)
                acc[o] += xf[o] * k0 + xf[o+1] * k1 + xf[o+2] * k2;
        }
    }
    size_t base = ((size_t)(b * CC + co) * HH + h) * HH + w0;
    float hf[8];
    #pragma unroll
    for (int o = 0; o < 8; ++o) {
        float hv = s_buf[(co * 18 + h + 1) * 20 + w0 + o + 1];
        hf[o] = 0.5f * hv + 0.5f * acc[o];
    }
    float4* fh = (float4*)(f_hat + base);
    float4* fr = (float4*)(f_rest + base);
    float4 v0 = fh[0], v1 = fh[1];
    v0.x += hf[0]; v0.y += hf[1]; v0.z += hf[2]; v0.w += hf[3];
    v1.x += hf[4]; v1.y += hf[5]; v1.z += hf[6]; v1.w += hf[7];
    fh[0] = v0; fh[1] = v1;
    float4 r0 = fr[0], r1 = fr[1];
    r0.x -= hf[0]; r0.y -= hf[1]; r0.z -= hf[2]; r0.w -= hf[3];
    r1.x -= hf[4]; r1.y -= hf[5]; r1.z -= hf[6]; r1.w -= hf[7];
    fr[0] = r0; fr[1] = r1;

    if (pnn > 0) {
        __syncthreads();
        float* fn = s_buf;
        float* d = &fn[(col * HH + h) * HH + w0];
        d[0] = r0.x; d[1] = r0.y; d[2] = r0.z; d[3] = r0.w;
        d[4] = r1.x; d[5] = r1.y; d[6] = r1.z; d[7] = r1.w;
        __syncthreads();
        int P2 = pnn * pnn;
        for (int i = t; i < P2 * 8; i += 256) {
            int cl = i & 7, pq = i >> 3;
            int q2 = pq % pnn, p2 = pq / pnn;
            int sp = (p2 * HH) / pnn, ep = ((p2 + 1) * HH + pnn - 1) / pnn;
            int sq = (q2 * HH) / pnn, eq = ((q2 + 1) * HH + pnn - 1) / pnn;
            float wgt = 1.0f / ((float)(ep - sp) * (float)(eq - sq));
            float sum = 0.f;
            for (int h2 = sp; h2 < ep; ++h2)
                for (int w2 = sq; w2 < eq; ++w2)
                    sum += fn[(cl * HH + h2) * HH + w2];
            z_next[((size_t)(b * P2 + pq)) * CC + cog * 8 + cl] = sum * wgt;
        }
    }
}

extern "C" void kernel_launch(void* const* d_in, const int* in_sizes, int n_in,
                              void* d_out, int out_size, void* d_ws, size_t ws_size,
                              hipStream_t stream) {
    const float* f  = (const float*)d_in[0];
    const float* E  = (const float*)d_in[1];
    const float* pw = (const float*)d_in[2];
    const float* pb = (const float*)d_in[3];
    float* out = (float*)d_out;

    // pn13 wants G=64 => 692224 keys; only if ws allows (R7-proven footprint).
    size_t fixed_f = (size_t)NTOT + VV + (size_t)16384 * CC;  // floats
    bool big_ws = ws_size >= fixed_f * 4 + (size_t)692224 * 8;
    size_t bk_elems = big_ws ? 692224 : 524288;
    int g13 = big_ws ? 64 : 32;

    float* wsf    = (float*)d_ws;
    float* f_rest = wsf;
    float* e2     = wsf + (size_t)NTOT;
    unsigned long long* bestk = (unsigned long long*)(e2 + VV);
    float* z      = (float*)(bestk + bk_elems);

    int phik[10];
    {
        double start = 1.0 / 3.0 / 4.0;
        double stop  = 1.0 - 1.0 / 3.0 / 4.0;
        double step  = (stop - start) / 3.0;
        double ticks[4];
        for (int i = 0; i < 4; ++i) ticks[i] = (double)i * step + start;
        ticks[3] = stop;
        for (int si = 0; si < 10; ++si) {
            double s = (double)si / 9.0;
            int bk = 0; double bd = fabs(ticks[0] - s);
            for (int tq = 1; tq < 4; ++tq) {
                double d2 = fabs(ticks[tq] - s);
                if (d2 < bd) { bd = d2; bk = tq; }
            }
            phik[si] = bk;
        }
    }

    static const int pns[10]  = {1, 2, 3, 4, 5, 6, 8, 10, 13, 16};
    static const int grpS[10] = {256, 128, 64, 32, 32, 16, 0, 0, 0, 0};
    int grpB[10] = {0, 0, 0, 0, 0, 0, 128, 64, g13, 32};

    init_k<<<(NTOT + 255) / 256, 256, 0, stream>>>(f, E, f_rest, out, e2, z);

    for (int si = 0; si < 10; ++si) {
        int pn = pns[si];
        int P = pn * pn;
        int M = BB * P;
        int G, TPP;
        if (pn <= 6) {
            int grp = grpS[si];
            G = grp * 4;
            int gsz = VV / G;
            argsmall_k<<<dim3(P, grp), 256, 0, stream>>>(z, E, e2, bestk, M, G, gsz);
        } else {
            G = grpB[si];
            int gsz = VV / G;
            int bx = (M + 511) / 512;
            dim3 ag(bx, G);
            argbig_k<<<ag, 256, 0, stream>>>(z, E, e2, bestk, M, G, gsz);
        }
        TPP = 1;
        while (TPP * 2 * P <= 256) TPP *= 2;
        int pnn = (si < 9) ? pns[si + 1] : 0;
        fuse_k<<<dim3(4, BB), 256, 0, stream>>>(bestk, E, pw, pb,
                                                out, f_rest, z,
                                                pn, G, TPP, phik[si], pnn);
    }
}